// Round 9
// baseline (131.364 us; speedup 1.0000x reference)
//
#include <hip/hip_runtime.h>
#include <hip/hip_bf16.h>

// Chamfer distance: B=4, S=4, N=M=4096, D=3, fp32 in/out.
// out[s*B + b] = mean_n min_m d2(n,m) + mean_m min_n d2(n,m)
//
// R9: two transposed MFMA passes so BOTH directions are register-accumulated.
// R8's single-G design needed a cross-lane col-max per tile (tree+shfl+ds_write
// serial after each MFMA) -> 566cyc/tile latency chain, MfmaUtil 5%. Here:
//   dir0: G  = A(queries) x B(refs)^T  -> row-max = dist1
//   dir1: G^T = A(refs)  x B(queries)^T -> row-max = dist2
// Epilogue per tile = 16 fmax into rowM[16] (v_max3 merges 2 tiles), nothing
// cross-lane until the very end. MFMA count doubles but matrix pipe is only
// ~1.7us total. B-frags staged to LDS (32KB chunks, shared by 4 waves).
//
// Precision: fp32 -> bf16 hi+lo split; K=16 slots carry all hi/lo cross
// products AND folded norm terms (nA = -|a|^2/2 with the A pattern, nB with B):
//   A[k] = [xh,xl,xh,xl, yh,yl,yh,yl, zh,zl,zh,zl, 1,1, nh,nl]
//   B[k] = [xh,xh,xl,xl, yh,yh,yl,yl, zh,zh,zl,zl, nh,nl, 1,1]
// dot = a.b - |a|^2/2 - |b|^2/2 = -d2/2; err ~1e-4 << 1.48e-3 threshold.
// min d2 = max(-2 * max G, 0).

constexpr int BB = 4, NPTS = 4096, PAIRS = 16;
constexpr int TPB = 256;                       // 4 waves
constexpr size_t ARR_ELEMS = (size_t)PAIRS * NPTS * 16;   // bf16 elems per packed array
// ws layout (bf16 elems): [outA][tgtB][tgtA][outB], 2 MB each
constexpr size_t WS_NEED = 4 * ARR_ELEMS * 2;

typedef __bf16 bf16x8 __attribute__((ext_vector_type(8)));
typedef float f32x16 __attribute__((ext_vector_type(16)));

// ---- pack: each point -> A-pattern row and B-pattern row ----
__global__ void pack2_kernel(const float* __restrict__ outp,
                             const float* __restrict__ tgtp,
                             __bf16* __restrict__ ws) {
  const int idx = blockIdx.x * TPB + threadIdx.x;   // 0..131071
  const int src = idx >> 16;                         // 0 = out_pts, 1 = tgt_pts
  const int pn  = idx & 65535;                       // pair*4096 + n
  const float* p = (src ? tgtp : outp) + (size_t)pn * 3;
  const float x = p[0], y = p[1], z = p[2];
  const float n2 = -0.5f * (x * x + y * y + z * z);
  const __bf16 xh = (__bf16)x, yh = (__bf16)y, zh = (__bf16)z, nh = (__bf16)n2;
  const __bf16 xl = (__bf16)(x - (float)xh);
  const __bf16 yl = (__bf16)(y - (float)yh);
  const __bf16 zl = (__bf16)(z - (float)zh);
  const __bf16 nl = (__bf16)(n2 - (float)nh);
  const __bf16 one = (__bf16)1.0f;

  union { __bf16 h[16]; uint4 q[2]; } u;
  // A pattern
  u.h[0]=xh; u.h[1]=xl; u.h[2]=xh; u.h[3]=xl;
  u.h[4]=yh; u.h[5]=yl; u.h[6]=yh; u.h[7]=yl;
  u.h[8]=zh; u.h[9]=zl; u.h[10]=zh; u.h[11]=zl;
  u.h[12]=one; u.h[13]=one; u.h[14]=nh; u.h[15]=nl;
  __bf16* aDst = ws + (src ? 2 : 0) * ARR_ELEMS + (size_t)pn * 16;
  ((uint4*)aDst)[0] = u.q[0]; ((uint4*)aDst)[1] = u.q[1];
  // B pattern
  u.h[0]=xh; u.h[1]=xh; u.h[2]=xl; u.h[3]=xl;
  u.h[4]=yh; u.h[5]=yh; u.h[6]=yl; u.h[7]=yl;
  u.h[8]=zh; u.h[9]=zh; u.h[10]=zl; u.h[11]=zl;
  u.h[12]=nh; u.h[13]=nl; u.h[14]=one; u.h[15]=one;
  __bf16* bDst = ws + (src ? 1 : 3) * ARR_ELEMS + (size_t)pn * 16;
  ((uint4*)bDst)[0] = u.q[0]; ((uint4*)bDst)[1] = u.q[1];
}

// ---- main: block = (row-group, pair, dir); wave w owns rows rg*128+w*32..+32
__global__ __launch_bounds__(TPB, 4)
void chamfer_mfma2_kernel(const __bf16* __restrict__ ws,
                          float* __restrict__ out) {
  const int t = threadIdx.x, l = t & 63, w = t >> 6;
  const int c32 = l & 31, h = l >> 5;
  const int rg = blockIdx.x, pair = blockIdx.y, dir = blockIdx.z;

  const __bf16* aArr = ws + (dir ? 2 : 0) * ARR_ELEMS;   // dir0: queries-A, dir1: refs-A
  const __bf16* bArr = ws + (dir ? 3 : 1) * ARR_ELEMS;   // dir0: refs-B,    dir1: queries-B

  __shared__ __bf16 sB[1024 * 16];   // 32 KB: one 1024-col chunk of B rows

  // Persistent A fragment: A[m = lane&31][k = 8*(lane>>5) + j]
  const int row = rg * 128 + w * 32 + c32;
  const bf16x8 afrag =
      *(const bf16x8*)(aArr + ((size_t)pair * NPTS + row) * 16 + (size_t)h * 8);

  f32x16 zacc;
  #pragma unroll
  for (int i = 0; i < 16; ++i) zacc[i] = 0.0f;
  float rowM[16];
  #pragma unroll
  for (int i = 0; i < 16; ++i) rowM[i] = -3.0e38f;

  const uint4* gsrc = (const uint4*)(bArr + (size_t)pair * NPTS * 16);
  uint4* lb = (uint4*)sB;

  for (int chunk = 0; chunk < 4; ++chunk) {
    __syncthreads();                  // previous chunk fully consumed
    const uint4* gs = gsrc + (size_t)chunk * 2048;
    #pragma unroll
    for (int i = 0; i < 8; ++i) lb[t + i * TPB] = gs[t + i * TPB];
    __syncthreads();

    // 32 col-tiles per chunk, 2 per iteration (max3 merge).
    #pragma unroll 2
    for (int ct = 0; ct < 16; ++ct) {
      const bf16x8 b0 =
          *(const bf16x8*)(sB + ((size_t)(ct * 64 + c32)) * 16 + h * 8);
      const bf16x8 b1 =
          *(const bf16x8*)(sB + ((size_t)(ct * 64 + 32 + c32)) * 16 + h * 8);
      const f32x16 a0 =
          __builtin_amdgcn_mfma_f32_32x32x16_bf16(afrag, b0, zacc, 0, 0, 0);
      const f32x16 a1 =
          __builtin_amdgcn_mfma_f32_32x32x16_bf16(afrag, b1, zacc, 0, 0, 0);
      #pragma unroll
      for (int i = 0; i < 16; ++i)
        rowM[i] = fmaxf(fmaxf(rowM[i], a0[i]), a1[i]);   // v_max3_f32
    }
  }

  // Cross-lane (once): max over the 32 cols resident in lanes' c32 bits.
  #pragma unroll
  for (int m = 1; m < 32; m <<= 1) {
    #pragma unroll
    for (int i = 0; i < 16; ++i)
      rowM[i] = fmaxf(rowM[i], __shfl_xor(rowM[i], m, 64));
  }
  float s = 0.0f;
  #pragma unroll
  for (int i = 0; i < 16; ++i) s += fmaxf(-2.0f * rowM[i], 0.0f);  // 16 rows (this h)
  s += __shfl_xor(s, 32, 64);        // + other half's 16 rows
  if (l == 0) {
    const int b = pair >> 2, sx = pair & 3;   // pair = b*S + s
    atomicAdd(&out[sx * BB + b], s * (1.0f / NPTS));
  }
}

// ---- R7 fallback (fp32 VALU, pk_fma) if ws is too small ----
typedef float v2f __attribute__((ext_vector_type(2)));
#define PK_FMA_ZW(g, q, rzw)                                              \
  asm("v_pk_fma_f32 %0, %1, %2, %2 op_sel:[0,0,1] op_sel_hi:[1,0,1]"      \
      : "=v"(g) : "v"(q), "v"(rzw))
#define PK_FMA_Y(g, q, rxy)                                               \
  asm("v_pk_fma_f32 %0, %1, %2, %0 op_sel:[0,1,0] op_sel_hi:[1,1,1]"      \
      : "+v"(g) : "v"(q), "v"(rxy))
#define PK_FMA_X(g, q, rxy)                                               \
  asm("v_pk_fma_f32 %0, %1, %2, %0 op_sel:[0,0,0] op_sel_hi:[1,0,1]"      \
      : "+v"(g) : "v"(q), "v"(rxy))

__global__ __launch_bounds__(1024, 4)
void chamfer_pk3_kernel(const float* __restrict__ out_pts,
                        const float* __restrict__ tgt_pts,
                        float* __restrict__ out) {
  const int t = threadIdx.x, l = t & 63, wid = t >> 6;
  const int qtile = blockIdx.x, pair = blockIdx.y, dir = blockIdx.z;
  const float* qbase = (dir == 0 ? out_pts : tgt_pts) + (size_t)pair * NPTS * 3;
  const float* rbase = (dir == 0 ? tgt_pts : out_pts) + (size_t)pair * NPTS * 3;
  __shared__ float4 sref[NPTS];
  #pragma unroll
  for (int k = 0; k < 4; ++k) {
    const int i = t + k * 1024;
    const float rx = rbase[3*i], ry = rbase[3*i+1], rz = rbase[3*i+2];
    sref[i] = make_float4(rx, ry, rz, -0.5f * (rx*rx + ry*ry + rz*rz));
  }
  v2f qx[4], qy[4], qz[4];
  #pragma unroll
  for (int p = 0; p < 4; ++p) {
    const int q0 = qtile * 512 + (2*p)*64 + l, q1 = q0 + 64;
    qx[p] = v2f{qbase[3*q0],   qbase[3*q1]};
    qy[p] = v2f{qbase[3*q0+1], qbase[3*q1+1]};
    qz[p] = v2f{qbase[3*q0+2], qbase[3*q1+2]};
  }
  float acc[8];
  #pragma unroll
  for (int j = 0; j < 8; ++j) acc[j] = -3.0e38f;
  __syncthreads();
  const int base = wid * 256;
  #pragma unroll 2
  for (int r = 0; r < 256; r += 2) {
    const float4 rf0 = sref[base + r], rf1 = sref[base + r + 1];
    v2f rxy0{rf0.x, rf0.y}, rzw0{rf0.z, rf0.w};
    v2f rxy1{rf1.x, rf1.y}, rzw1{rf1.z, rf1.w};
    #pragma unroll
    for (int p = 0; p < 4; ++p) {
      v2f g0, g1;
      PK_FMA_ZW(g0, qz[p], rzw0); PK_FMA_Y(g0, qy[p], rxy0); PK_FMA_X(g0, qx[p], rxy0);
      PK_FMA_ZW(g1, qz[p], rzw1); PK_FMA_Y(g1, qy[p], rxy1); PK_FMA_X(g1, qx[p], rxy1);
      acc[2*p]   = fmaxf(fmaxf(acc[2*p],   g0.x), g1.x);
      acc[2*p+1] = fmaxf(fmaxf(acc[2*p+1], g0.y), g1.y);
    }
  }
  __syncthreads();
  float* Sf = reinterpret_cast<float*>(sref);
  #pragma unroll
  for (int j = 0; j < 8; ++j) Sf[wid * 512 + j * 64 + l] = acc[j];
  __syncthreads();
  if (t < 512) {
    float g = Sf[t];
    #pragma unroll
    for (int w2 = 1; w2 < 16; ++w2) g = fmaxf(g, Sf[w2 * 512 + t]);
    const int j = t >> 6, p = j >> 1, hh = j & 1;
    const float x2 = qx[p][hh]*qx[p][hh] + qy[p][hh]*qy[p][hh] + qz[p][hh]*qz[p][hh];
    float d = fmaxf(fmaf(-2.0f, g, x2), 0.0f);
    #pragma unroll
    for (int off = 1; off < 64; off <<= 1) d += __shfl_xor(d, off, 64);
    if (l == 0) Sf[16 * 512 + (t >> 6)] = d;
  }
  __syncthreads();
  if (t == 0) {
    float ssum = 0.0f;
    #pragma unroll
    for (int w2 = 0; w2 < 8; ++w2) ssum += Sf[16 * 512 + w2];
    const int b = pair >> 2, sx = pair & 3;
    atomicAdd(&out[sx * BB + b], ssum * (1.0f / NPTS));
  }
}

extern "C" void kernel_launch(void* const* d_in, const int* in_sizes, int n_in,
                              void* d_out, int out_size, void* d_ws, size_t ws_size,
                              hipStream_t stream) {
  const float* out_pts = (const float*)d_in[0];
  const float* tgt_pts = (const float*)d_in[1];
  float* out = (float*)d_out;

  hipMemsetAsync(out, 0, out_size * sizeof(float), stream);
  if (ws_size >= WS_NEED) {
    __bf16* ws = (__bf16*)d_ws;
    pack2_kernel<<<2 * PAIRS * NPTS / TPB, TPB, 0, stream>>>(out_pts, tgt_pts, ws);
    chamfer_mfma2_kernel<<<dim3(32, PAIRS, 2), TPB, 0, stream>>>(ws, out);
  } else {
    chamfer_pk3_kernel<<<dim3(8, PAIRS, 2), 1024, 0, stream>>>(out_pts, tgt_pts, out);
  }
}

// Round 10
// 110.728 us; speedup vs baseline: 1.1864x; 1.1864x over previous
//
#include <hip/hip_runtime.h>
#include <hip/hip_bf16.h>

// Chamfer distance: B=4, S=4, N=M=4096, D=3, fp32 in/out.
// out[s*B + b] = mean_n min_m d2(n,m) + mean_m min_n d2(n,m)
//
// R10: two transposed MFMA passes (register-accumulated row-max both dirs,
// as R9) but NO LDS in the hot path. R9 stalled on 8-way LDS bank conflicts
// (2.1M cyc) + ds_read->MFMA->max3 serial chains. Key insight: a 32x32 tile's
// B-fragment is a PERMUTATION of a contiguous 1024B block (lane l reads 16B
// granule (l&31)*2 + (l>>5)) -> a direct global read is fully coalesced (16
// full 64B lines) and rides the deep vmcnt queue; the compiler pipelines it.
// Each wave carries 2 row-tiles (2 A-frags) so each B-frag feeds 2 MFMAs:
// B traffic = 2048 waves x 128KB = 256MB from L2 ~ 7.4us floor.
// XCD swizzle: problem = blockIdx.x % 32 -> a problem's 8 blocks hit the same
// XCD (round-robin dispatch), B-stream stays resident in that XCD's L2.
//
// Precision: fp32 -> bf16 hi+lo split; K=16 slots carry all hi/lo cross
// products AND folded norm terms (-|p|^2/2):
//   A[k] = [xh,xl,xh,xl, yh,yl,yh,yl, zh,zl,zh,zl, 1,1, nh,nl]
//   B[k] = [xh,xh,xl,xl, yh,yh,yl,yl, zh,zh,zl,zl, nh,nl, 1,1]
// dot = a.b - |a|^2/2 - |b|^2/2 = -d2/2; min d2 = max(-2*maxG, 0);
// err ~1e-4 << 1.48e-3 threshold (verified exact vs harness in R8/R9).
// C/D layout (m74/m101): col=lane&31, row=(reg&3)+8*(reg>>2)+4*(lane>>5).

constexpr int BB = 4, NPTS = 4096, PAIRS = 16;
constexpr size_t ARR_ELEMS = (size_t)PAIRS * NPTS * 16;   // bf16 elems per packed array
// ws layout (bf16): [outA][tgtB][tgtA][outB], 2 MB each
constexpr size_t WS_NEED = 4 * ARR_ELEMS * 2;

typedef __bf16 bf16x8 __attribute__((ext_vector_type(8)));
typedef float f32x16 __attribute__((ext_vector_type(16)));

// ---- pack: each point -> A-pattern row and B-pattern row ----
__global__ void pack2_kernel(const float* __restrict__ outp,
                             const float* __restrict__ tgtp,
                             __bf16* __restrict__ ws) {
  const int idx = blockIdx.x * 256 + threadIdx.x;   // 0..131071
  const int src = idx >> 16;                         // 0 = out_pts, 1 = tgt_pts
  const int pn  = idx & 65535;                       // pair*4096 + n
  const float* p = (src ? tgtp : outp) + (size_t)pn * 3;
  const float x = p[0], y = p[1], z = p[2];
  const float n2 = -0.5f * (x * x + y * y + z * z);
  const __bf16 xh = (__bf16)x, yh = (__bf16)y, zh = (__bf16)z, nh = (__bf16)n2;
  const __bf16 xl = (__bf16)(x - (float)xh);
  const __bf16 yl = (__bf16)(y - (float)yh);
  const __bf16 zl = (__bf16)(z - (float)zh);
  const __bf16 nl = (__bf16)(n2 - (float)nh);
  const __bf16 one = (__bf16)1.0f;

  union { __bf16 h[16]; uint4 q[2]; } u;
  // A pattern
  u.h[0]=xh; u.h[1]=xl; u.h[2]=xh; u.h[3]=xl;
  u.h[4]=yh; u.h[5]=yl; u.h[6]=yh; u.h[7]=yl;
  u.h[8]=zh; u.h[9]=zl; u.h[10]=zh; u.h[11]=zl;
  u.h[12]=one; u.h[13]=one; u.h[14]=nh; u.h[15]=nl;
  __bf16* aDst = ws + (src ? 2 : 0) * ARR_ELEMS + (size_t)pn * 16;
  ((uint4*)aDst)[0] = u.q[0]; ((uint4*)aDst)[1] = u.q[1];
  // B pattern
  u.h[0]=xh; u.h[1]=xh; u.h[2]=xl; u.h[3]=xl;
  u.h[4]=yh; u.h[5]=yh; u.h[6]=yl; u.h[7]=yl;
  u.h[8]=zh; u.h[9]=zh; u.h[10]=zl; u.h[11]=zl;
  u.h[12]=nh; u.h[13]=nl; u.h[14]=one; u.h[15]=one;
  __bf16* bDst = ws + (src ? 1 : 3) * ARR_ELEMS + (size_t)pn * 16;
  ((uint4*)bDst)[0] = u.q[0]; ((uint4*)bDst)[1] = u.q[1];
}

// ---- main: 256 blocks x 512 thr (8 waves). Block -> (rg, pair, dir) via
// problem = blockIdx.x % 32 (XCD-resident B-stream). Wave w owns rows
// rg*512 + w*64 .. +64 (two 32-row tiles). No LDS, no barriers.
__global__ __launch_bounds__(512, 2)
void chamfer_mfma3_kernel(const __bf16* __restrict__ ws,
                          float* __restrict__ out) {
  const int t = threadIdx.x, l = t & 63, w = t >> 6;
  const int c32 = l & 31, h = l >> 5;
  const int blk = blockIdx.x;
  const int prob = blk & 31;          // same-problem blocks -> same XCD
  const int rg   = blk >> 5;          // 0..7
  const int pair = prob & 15;
  const int dir  = prob >> 4;

  const __bf16* aArr = ws + (dir ? 2 : 0) * ARR_ELEMS;  // dir0: queries, dir1: refs
  const __bf16* bArr = ws + (dir ? 3 : 1) * ARR_ELEMS;  // dir0: refs, dir1: queries

  // Two persistent A fragments: rows rg*512 + w*64 (+32).
  const size_t arow = (size_t)pair * NPTS + rg * 512 + w * 64 + c32;
  const bf16x8 af0 = *(const bf16x8*)(aArr + (arow)      * 16 + (size_t)h * 8);
  const bf16x8 af1 = *(const bf16x8*)(aArr + (arow + 32) * 16 + (size_t)h * 8);

  f32x16 zacc;
  #pragma unroll
  for (int i = 0; i < 16; ++i) zacc[i] = 0.0f;
  float rowM0[16], rowM1[16];
  #pragma unroll
  for (int i = 0; i < 16; ++i) { rowM0[i] = -3.0e38f; rowM1[i] = -3.0e38f; }

  // B fragment stream: tile ct -> lane reads 16B at (ct*32 + c32)*32 + h*16.
  // Per wave per tile: one contiguous (permuted) 1024B block.
  const __bf16* bfr = bArr + (size_t)pair * NPTS * 16 + (size_t)c32 * 16 + (size_t)h * 8;

  #pragma unroll 4
  for (int ct = 0; ct < 128; ct += 2) {
    const bf16x8 b0 = *(const bf16x8*)(bfr + (size_t)(ct * 32) * 16);
    const bf16x8 b1 = *(const bf16x8*)(bfr + (size_t)(ct * 32 + 32) * 16);
    const f32x16 a00 = __builtin_amdgcn_mfma_f32_32x32x16_bf16(af0, b0, zacc, 0, 0, 0);
    const f32x16 a01 = __builtin_amdgcn_mfma_f32_32x32x16_bf16(af0, b1, zacc, 0, 0, 0);
    const f32x16 a10 = __builtin_amdgcn_mfma_f32_32x32x16_bf16(af1, b0, zacc, 0, 0, 0);
    const f32x16 a11 = __builtin_amdgcn_mfma_f32_32x32x16_bf16(af1, b1, zacc, 0, 0, 0);
    #pragma unroll
    for (int i = 0; i < 16; ++i) {
      rowM0[i] = fmaxf(fmaxf(rowM0[i], a00[i]), a01[i]);   // v_max3_f32
      rowM1[i] = fmaxf(fmaxf(rowM1[i], a10[i]), a11[i]);   // v_max3_f32
    }
  }

  // Cross-lane max over the 32 cols resident in c32 (once per wave).
  #pragma unroll
  for (int m = 1; m < 32; m <<= 1) {
    #pragma unroll
    for (int i = 0; i < 16; ++i) {
      rowM0[i] = fmaxf(rowM0[i], __shfl_xor(rowM0[i], m, 64));
      rowM1[i] = fmaxf(rowM1[i], __shfl_xor(rowM1[i], m, 64));
    }
  }
  float s = 0.0f;
  #pragma unroll
  for (int i = 0; i < 16; ++i)
    s += fmaxf(-2.0f * rowM0[i], 0.0f) + fmaxf(-2.0f * rowM1[i], 0.0f);
  s += __shfl_xor(s, 32, 64);        // other half-wave's 16 rows per tile
  if (l == 0) {
    const int bb = pair >> 2, sx = pair & 3;   // pair = b*S + s
    atomicAdd(&out[sx * BB + bb], s * (1.0f / NPTS));
  }
}

// ---- R7 fallback (fp32 VALU, pk_fma) if ws is too small ----
typedef float v2f __attribute__((ext_vector_type(2)));
#define PK_FMA_ZW(g, q, rzw)                                              \
  asm("v_pk_fma_f32 %0, %1, %2, %2 op_sel:[0,0,1] op_sel_hi:[1,0,1]"      \
      : "=v"(g) : "v"(q), "v"(rzw))
#define PK_FMA_Y(g, q, rxy)                                               \
  asm("v_pk_fma_f32 %0, %1, %2, %0 op_sel:[0,1,0] op_sel_hi:[1,1,1]"      \
      : "+v"(g) : "v"(q), "v"(rxy))
#define PK_FMA_X(g, q, rxy)                                               \
  asm("v_pk_fma_f32 %0, %1, %2, %0 op_sel:[0,0,0] op_sel_hi:[1,0,1]"      \
      : "+v"(g) : "v"(q), "v"(rxy))

__global__ __launch_bounds__(1024, 4)
void chamfer_pk3_kernel(const float* __restrict__ out_pts,
                        const float* __restrict__ tgt_pts,
                        float* __restrict__ out) {
  const int t = threadIdx.x, l = t & 63, wid = t >> 6;
  const int qtile = blockIdx.x, pair = blockIdx.y, dir = blockIdx.z;
  const float* qbase = (dir == 0 ? out_pts : tgt_pts) + (size_t)pair * NPTS * 3;
  const float* rbase = (dir == 0 ? tgt_pts : out_pts) + (size_t)pair * NPTS * 3;
  __shared__ float4 sref[NPTS];
  #pragma unroll
  for (int k = 0; k < 4; ++k) {
    const int i = t + k * 1024;
    const float rx = rbase[3*i], ry = rbase[3*i+1], rz = rbase[3*i+2];
    sref[i] = make_float4(rx, ry, rz, -0.5f * (rx*rx + ry*ry + rz*rz));
  }
  v2f qx[4], qy[4], qz[4];
  #pragma unroll
  for (int p = 0; p < 4; ++p) {
    const int q0 = qtile * 512 + (2*p)*64 + l, q1 = q0 + 64;
    qx[p] = v2f{qbase[3*q0],   qbase[3*q1]};
    qy[p] = v2f{qbase[3*q0+1], qbase[3*q1+1]};
    qz[p] = v2f{qbase[3*q0+2], qbase[3*q1+2]};
  }
  float acc[8];
  #pragma unroll
  for (int j = 0; j < 8; ++j) acc[j] = -3.0e38f;
  __syncthreads();
  const int base = wid * 256;
  #pragma unroll 2
  for (int r = 0; r < 256; r += 2) {
    const float4 rf0 = sref[base + r], rf1 = sref[base + r + 1];
    v2f rxy0{rf0.x, rf0.y}, rzw0{rf0.z, rf0.w};
    v2f rxy1{rf1.x, rf1.y}, rzw1{rf1.z, rf1.w};
    #pragma unroll
    for (int p = 0; p < 4; ++p) {
      v2f g0, g1;
      PK_FMA_ZW(g0, qz[p], rzw0); PK_FMA_Y(g0, qy[p], rxy0); PK_FMA_X(g0, qx[p], rxy0);
      PK_FMA_ZW(g1, qz[p], rzw1); PK_FMA_Y(g1, qy[p], rxy1); PK_FMA_X(g1, qx[p], rxy1);
      acc[2*p]   = fmaxf(fmaxf(acc[2*p],   g0.x), g1.x);
      acc[2*p+1] = fmaxf(fmaxf(acc[2*p+1], g0.y), g1.y);
    }
  }
  __syncthreads();
  float* Sf = reinterpret_cast<float*>(sref);
  #pragma unroll
  for (int j = 0; j < 8; ++j) Sf[wid * 512 + j * 64 + l] = acc[j];
  __syncthreads();
  if (t < 512) {
    float g = Sf[t];
    #pragma unroll
    for (int w2 = 1; w2 < 16; ++w2) g = fmaxf(g, Sf[w2 * 512 + t]);
    const int j = t >> 6, p = j >> 1, hh = j & 1;
    const float x2 = qx[p][hh]*qx[p][hh] + qy[p][hh]*qy[p][hh] + qz[p][hh]*qz[p][hh];
    float d = fmaxf(fmaf(-2.0f, g, x2), 0.0f);
    #pragma unroll
    for (int off = 1; off < 64; off <<= 1) d += __shfl_xor(d, off, 64);
    if (l == 0) Sf[16 * 512 + (t >> 6)] = d;
  }
  __syncthreads();
  if (t == 0) {
    float ssum = 0.0f;
    #pragma unroll
    for (int w2 = 0; w2 < 8; ++w2) ssum += Sf[16 * 512 + w2];
    const int b = pair >> 2, sx = pair & 3;
    atomicAdd(&out[sx * BB + b], ssum * (1.0f / NPTS));
  }
}

extern "C" void kernel_launch(void* const* d_in, const int* in_sizes, int n_in,
                              void* d_out, int out_size, void* d_ws, size_t ws_size,
                              hipStream_t stream) {
  const float* out_pts = (const float*)d_in[0];
  const float* tgt_pts = (const float*)d_in[1];
  float* out = (float*)d_out;

  hipMemsetAsync(out, 0, out_size * sizeof(float), stream);
  if (ws_size >= WS_NEED) {
    __bf16* ws = (__bf16*)d_ws;
    pack2_kernel<<<2 * PAIRS * NPTS / 256, 256, 0, stream>>>(out_pts, tgt_pts, ws);
    chamfer_mfma3_kernel<<<256, 512, 0, stream>>>(ws, out);
  } else {
    chamfer_pk3_kernel<<<dim3(8, PAIRS, 2), 1024, 0, stream>>>(out_pts, tgt_pts, out);
  }
}

// Round 11
// 109.838 us; speedup vs baseline: 1.1960x; 1.0081x over previous
//
#include <hip/hip_runtime.h>
#include <hip/hip_bf16.h>

// Chamfer distance: B=4, S=4, N=M=4096, D=3, fp32 in/out.
// out[s*B + b] = mean_n min_m d2(n,m) + mean_m min_n d2(n,m)
//
// R11: R10's global-streamed MFMA (no LDS in hot path, coalesced permuted
// 1KB B-frag blocks) + two fixes for R10's exposed-latency stall
// (VGPR=52 showed the compiler kept NO loads in flight; 2 waves/SIMD):
//  1. manual 4-buffer register prefetch, distance 2 half-iters (~200cyc) ->
//     load-use decoupled, partial vmcnt waits instead of full stalls.
//  2. col-range split per wave: 1024 blocks x 256 thr = 4 waves/SIMD.
//     Wave (rp,ch) does 2 row-tiles x 64 col-tiles; halves merged via 1KB LDS.
// Two transposed passes keep both chamfer directions register-accumulated
// row-maxes (R9 lesson: per-tile cross-lane epilogues serialize).
//
// Precision: fp32 -> bf16 hi+lo split; K=16 slots carry all hi/lo cross
// products AND folded norm terms (-|p|^2/2):
//   A[k] = [xh,xl,xh,xl, yh,yl,yh,yl, zh,zl,zh,zl, 1,1, nh,nl]
//   B[k] = [xh,xh,xl,xl, yh,yh,yl,yl, zh,zh,zl,zl, nh,nl, 1,1]
// dot = a.b - |a|^2/2 - |b|^2/2 = -d2/2; min d2 = max(-2*maxG, 0);
// err ~1e-4 << 1.48e-3 (absmax 0.0 in R8-R10).
// C/D layout (m74/m101): col=lane&31, row=(reg&3)+8*(reg>>2)+4*(lane>>5).

constexpr int BB = 4, NPTS = 4096, PAIRS = 16;
constexpr size_t ARR_ELEMS = (size_t)PAIRS * NPTS * 16;   // bf16 elems per packed array
// ws layout (bf16): [outA][tgtB][tgtA][outB], 2 MB each; + prefetch over-read pad
constexpr size_t WS_NEED = 4 * ARR_ELEMS * 2 + 8192;

typedef __bf16 bf16x8 __attribute__((ext_vector_type(8)));
typedef float f32x16 __attribute__((ext_vector_type(16)));

// ---- pack: each point -> A-pattern row and B-pattern row ----
__global__ void pack2_kernel(const float* __restrict__ outp,
                             const float* __restrict__ tgtp,
                             __bf16* __restrict__ ws) {
  const int idx = blockIdx.x * 256 + threadIdx.x;   // 0..131071
  const int src = idx >> 16;                         // 0 = out_pts, 1 = tgt_pts
  const int pn  = idx & 65535;                       // pair*4096 + n
  const float* p = (src ? tgtp : outp) + (size_t)pn * 3;
  const float x = p[0], y = p[1], z = p[2];
  const float n2 = -0.5f * (x * x + y * y + z * z);
  const __bf16 xh = (__bf16)x, yh = (__bf16)y, zh = (__bf16)z, nh = (__bf16)n2;
  const __bf16 xl = (__bf16)(x - (float)xh);
  const __bf16 yl = (__bf16)(y - (float)yh);
  const __bf16 zl = (__bf16)(z - (float)zh);
  const __bf16 nl = (__bf16)(n2 - (float)nh);
  const __bf16 one = (__bf16)1.0f;

  union { __bf16 h[16]; uint4 q[2]; } u;
  // A pattern
  u.h[0]=xh; u.h[1]=xl; u.h[2]=xh; u.h[3]=xl;
  u.h[4]=yh; u.h[5]=yl; u.h[6]=yh; u.h[7]=yl;
  u.h[8]=zh; u.h[9]=zl; u.h[10]=zh; u.h[11]=zl;
  u.h[12]=one; u.h[13]=one; u.h[14]=nh; u.h[15]=nl;
  __bf16* aDst = ws + (src ? 2 : 0) * ARR_ELEMS + (size_t)pn * 16;
  ((uint4*)aDst)[0] = u.q[0]; ((uint4*)aDst)[1] = u.q[1];
  // B pattern
  u.h[0]=xh; u.h[1]=xh; u.h[2]=xl; u.h[3]=xl;
  u.h[4]=yh; u.h[5]=yh; u.h[6]=yl; u.h[7]=yl;
  u.h[8]=zh; u.h[9]=zh; u.h[10]=zl; u.h[11]=zl;
  u.h[12]=nh; u.h[13]=nl; u.h[14]=one; u.h[15]=one;
  __bf16* bDst = ws + (src ? 1 : 3) * ARR_ELEMS + (size_t)pn * 16;
  ((uint4*)bDst)[0] = u.q[0]; ((uint4*)bDst)[1] = u.q[1];
}

// ---- main: grid (32 rowblocks, 16 pairs, 2 dirs), 256 thr (4 waves).
// Wave w: rowpair rp = w>>1 (rows rb*128 + rp*64 .. +64 = 2 row-tiles),
//         colhalf ch = w&1 (col-tiles ch*64 .. +64).
__global__ __launch_bounds__(256, 4)
void chamfer_mfma4_kernel(const __bf16* __restrict__ ws,
                          float* __restrict__ out) {
  const int t = threadIdx.x, l = t & 63, w = t >> 6;
  const int c32 = l & 31, h = l >> 5;
  const int rp = w >> 1, ch = w & 1;
  const int rb = blockIdx.x, pair = blockIdx.y, dir = blockIdx.z;

  const __bf16* aArr = ws + (dir ? 2 : 0) * ARR_ELEMS;  // dir0: queries, dir1: refs
  const __bf16* bArr = ws + (dir ? 3 : 1) * ARR_ELEMS;  // dir0: refs, dir1: queries

  // Two persistent A fragments: rows rb*128 + rp*64 (+32).
  const size_t arow = (size_t)pair * NPTS + rb * 128 + rp * 64 + c32;
  const bf16x8 af0 = *(const bf16x8*)(aArr + (arow)      * 16 + (size_t)h * 8);
  const bf16x8 af1 = *(const bf16x8*)(aArr + (arow + 32) * 16 + (size_t)h * 8);

  f32x16 zacc;
  #pragma unroll
  for (int i = 0; i < 16; ++i) zacc[i] = 0.0f;
  float rowM0[16], rowM1[16];
  #pragma unroll
  for (int i = 0; i < 16; ++i) { rowM0[i] = -3.0e38f; rowM1[i] = -3.0e38f; }

  // B-frag stream: tile ct (within this wave's half) at bbase + ct*512 elems.
  // Per tile per wave: one contiguous (lane-permuted) 1KB block -> coalesced.
  const __bf16* bbase =
      bArr + ((size_t)pair * NPTS + ch * 2048 + c32) * 16 + (size_t)h * 8;
  #define LT(tile) (*(const bf16x8*)(bbase + (size_t)(tile) * 512))

  // 4-buffer rotation, prefetch distance = 2 half-iters (4 tiles / ~4KB ahead;
  // ws padded for the tail over-read).
  bf16x8 buf0 = LT(0), buf1 = LT(1), buf2 = LT(2), buf3 = LT(3);

  #define HALF_STEP(bA, bB, t0)                                               \
    {                                                                         \
      const bf16x8 b0 = bA, b1 = bB;                                          \
      bA = LT(t0 + 4);                                                        \
      bB = LT(t0 + 5);                                                        \
      const f32x16 a00 = __builtin_amdgcn_mfma_f32_32x32x16_bf16(af0, b0, zacc, 0, 0, 0); \
      const f32x16 a01 = __builtin_amdgcn_mfma_f32_32x32x16_bf16(af0, b1, zacc, 0, 0, 0); \
      const f32x16 a10 = __builtin_amdgcn_mfma_f32_32x32x16_bf16(af1, b0, zacc, 0, 0, 0); \
      const f32x16 a11 = __builtin_amdgcn_mfma_f32_32x32x16_bf16(af1, b1, zacc, 0, 0, 0); \
      _Pragma("unroll")                                                       \
      for (int i = 0; i < 16; ++i) {                                          \
        rowM0[i] = fmaxf(fmaxf(rowM0[i], a00[i]), a01[i]);  /* v_max3 */      \
        rowM1[i] = fmaxf(fmaxf(rowM1[i], a10[i]), a11[i]);  /* v_max3 */      \
      }                                                                       \
    }

  for (int it = 0; it < 16; ++it) {
    HALF_STEP(buf0, buf1, 4 * it);
    HALF_STEP(buf2, buf3, 4 * it + 2);
  }
  #undef HALF_STEP
  #undef LT

  // Cross-lane max over the 32 cols resident in c32 (once per wave).
  #pragma unroll
  for (int m = 1; m < 32; m <<= 1) {
    #pragma unroll
    for (int i = 0; i < 16; ++i) {
      rowM0[i] = fmaxf(rowM0[i], __shfl_xor(rowM0[i], m, 64));
      rowM1[i] = fmaxf(rowM1[i], __shfl_xor(rowM1[i], m, 64));
    }
  }

  // Merge colhalves: sMax[wave][tile][h][reg], written by lanes c32==0.
  __shared__ float sMax[4 * 2 * 2 * 16];   // 1 KB
  if (c32 == 0) {
    #pragma unroll
    for (int i = 0; i < 16; ++i) {
      sMax[((w * 2 + 0) * 2 + h) * 16 + i] = rowM0[i];
      sMax[((w * 2 + 1) * 2 + h) * 16 + i] = rowM1[i];
    }
  }
  __syncthreads();

  // Threads 0..127 finalize one block-row each; 2 wave-sums -> 2 atomics.
  if (t < 128) {
    const int rpp = t >> 6, rr = t & 63;
    const int tile = rr >> 5, tr = rr & 31;
    const int hh = (tr >> 2) & 1, reg = (tr & 3) + 4 * (tr >> 3);
    const float g0 = sMax[(((2 * rpp + 0) * 2 + tile) * 2 + hh) * 16 + reg];
    const float g1 = sMax[(((2 * rpp + 1) * 2 + tile) * 2 + hh) * 16 + reg];
    float d = fmaxf(-2.0f * fmaxf(g0, g1), 0.0f);   // min squared distance
    #pragma unroll
    for (int off = 1; off < 64; off <<= 1) d += __shfl_xor(d, off, 64);
    if ((t & 63) == 0) {
      const int bb = pair >> 2, sx = pair & 3;      // pair = b*S + s
      atomicAdd(&out[sx * BB + bb], d * (1.0f / NPTS));
    }
  }
}

// ---- R7 fallback (fp32 VALU, pk_fma) if ws is too small ----
typedef float v2f __attribute__((ext_vector_type(2)));
#define PK_FMA_ZW(g, q, rzw)                                              \
  asm("v_pk_fma_f32 %0, %1, %2, %2 op_sel:[0,0,1] op_sel_hi:[1,0,1]"      \
      : "=v"(g) : "v"(q), "v"(rzw))
#define PK_FMA_Y(g, q, rxy)                                               \
  asm("v_pk_fma_f32 %0, %1, %2, %0 op_sel:[0,1,0] op_sel_hi:[1,1,1]"      \
      : "+v"(g) : "v"(q), "v"(rxy))
#define PK_FMA_X(g, q, rxy)                                               \
  asm("v_pk_fma_f32 %0, %1, %2, %0 op_sel:[0,0,0] op_sel_hi:[1,0,1]"      \
      : "+v"(g) : "v"(q), "v"(rxy))

__global__ __launch_bounds__(1024, 4)
void chamfer_pk3_kernel(const float* __restrict__ out_pts,
                        const float* __restrict__ tgt_pts,
                        float* __restrict__ out) {
  const int t = threadIdx.x, l = t & 63, wid = t >> 6;
  const int qtile = blockIdx.x, pair = blockIdx.y, dir = blockIdx.z;
  const float* qbase = (dir == 0 ? out_pts : tgt_pts) + (size_t)pair * NPTS * 3;
  const float* rbase = (dir == 0 ? tgt_pts : out_pts) + (size_t)pair * NPTS * 3;
  __shared__ float4 sref[NPTS];
  #pragma unroll
  for (int k = 0; k < 4; ++k) {
    const int i = t + k * 1024;
    const float rx = rbase[3*i], ry = rbase[3*i+1], rz = rbase[3*i+2];
    sref[i] = make_float4(rx, ry, rz, -0.5f * (rx*rx + ry*ry + rz*rz));
  }
  v2f qx[4], qy[4], qz[4];
  #pragma unroll
  for (int p = 0; p < 4; ++p) {
    const int q0 = qtile * 512 + (2*p)*64 + l, q1 = q0 + 64;
    qx[p] = v2f{qbase[3*q0],   qbase[3*q1]};
    qy[p] = v2f{qbase[3*q0+1], qbase[3*q1+1]};
    qz[p] = v2f{qbase[3*q0+2], qbase[3*q1+2]};
  }
  float acc[8];
  #pragma unroll
  for (int j = 0; j < 8; ++j) acc[j] = -3.0e38f;
  __syncthreads();
  const int base = wid * 256;
  #pragma unroll 2
  for (int r = 0; r < 256; r += 2) {
    const float4 rf0 = sref[base + r], rf1 = sref[base + r + 1];
    v2f rxy0{rf0.x, rf0.y}, rzw0{rf0.z, rf0.w};
    v2f rxy1{rf1.x, rf1.y}, rzw1{rf1.z, rf1.w};
    #pragma unroll
    for (int p = 0; p < 4; ++p) {
      v2f g0, g1;
      PK_FMA_ZW(g0, qz[p], rzw0); PK_FMA_Y(g0, qy[p], rxy0); PK_FMA_X(g0, qx[p], rxy0);
      PK_FMA_ZW(g1, qz[p], rzw1); PK_FMA_Y(g1, qy[p], rxy1); PK_FMA_X(g1, qx[p], rxy1);
      acc[2*p]   = fmaxf(fmaxf(acc[2*p],   g0.x), g1.x);
      acc[2*p+1] = fmaxf(fmaxf(acc[2*p+1], g0.y), g1.y);
    }
  }
  __syncthreads();
  float* Sf = reinterpret_cast<float*>(sref);
  #pragma unroll
  for (int j = 0; j < 8; ++j) Sf[wid * 512 + j * 64 + l] = acc[j];
  __syncthreads();
  if (t < 512) {
    float g = Sf[t];
    #pragma unroll
    for (int w2 = 1; w2 < 16; ++w2) g = fmaxf(g, Sf[w2 * 512 + t]);
    const int j = t >> 6, p = j >> 1, hh = j & 1;
    const float x2 = qx[p][hh]*qx[p][hh] + qy[p][hh]*qy[p][hh] + qz[p][hh]*qz[p][hh];
    float d = fmaxf(fmaf(-2.0f, g, x2), 0.0f);
    #pragma unroll
    for (int off = 1; off < 64; off <<= 1) d += __shfl_xor(d, off, 64);
    if (l == 0) Sf[16 * 512 + (t >> 6)] = d;
  }
  __syncthreads();
  if (t == 0) {
    float ssum = 0.0f;
    #pragma unroll
    for (int w2 = 0; w2 < 8; ++w2) ssum += Sf[16 * 512 + w2];
    const int b = pair >> 2, sx = pair & 3;
    atomicAdd(&out[sx * BB + b], ssum * (1.0f / NPTS));
  }
}

extern "C" void kernel_launch(void* const* d_in, const int* in_sizes, int n_in,
                              void* d_out, int out_size, void* d_ws, size_t ws_size,
                              hipStream_t stream) {
  const float* out_pts = (const float*)d_in[0];
  const float* tgt_pts = (const float*)d_in[1];
  float* out = (float*)d_out;

  hipMemsetAsync(out, 0, out_size * sizeof(float), stream);
  if (ws_size >= WS_NEED) {
    __bf16* ws = (__bf16*)d_ws;
    pack2_kernel<<<2 * PAIRS * NPTS / 256, 256, 0, stream>>>(out_pts, tgt_pts, ws);
    chamfer_mfma4_kernel<<<dim3(32, PAIRS, 2), 256, 0, stream>>>(ws, out);
  } else {
    chamfer_pk3_kernel<<<dim3(8, PAIRS, 2), 1024, 0, stream>>>(out_pts, tgt_pts, out);
  }
}